// Round 22
// baseline (461.129 us; speedup 1.0000x reference)
//
#include <hip/hip_runtime.h>
#include <hip/hip_bf16.h>

typedef short s16x8 __attribute__((ext_vector_type(8)));
typedef float f32x4 __attribute__((ext_vector_type(4)));
typedef unsigned short u16;
typedef unsigned int u32;

#define TB 32
#define NTHREADS 512

// prep-buffer element offsets (bf16 elements)
#define P_L1 0
#define P_L2 16384
#define P_L3 278528
#define P_L4 540672      // packets unused after fusion; first 4KB reused for biasF (f32)
#define P_H1 802816
#define P_H2 1327104
#define P_H3 1392640
#define P_H4 1409024
#define P_TOT 1413120
#define P_F  1413120     // fused W4@HW1 packets: 16 units x [kg4][1024n][8j]

// LDS (TB=32, 68KB -> 2 blocks/CU):
// buf0 [32][1024B] at 0; xs [32][128B] at 32K; buf1 [32][1024B] at 36K.
// y1 slices: 4 x [32][256B] = 8KB each inside buf1 at (g&3)*8192.
#define BUF0   0
#define XS_OFF 32768
#define BUF1   36864
#define LDS_BYTES 69632   // 68 KB

__device__ __forceinline__ u16 f2bf(float v) {
  __hip_bfloat16 b = __float2bfloat16(v);
  return __builtin_bit_cast(u16, b);
}
__device__ __forceinline__ float bf2f(u16 u) {
  u32 x = ((u32)u) << 16;
  return __builtin_bit_cast(float, x);
}

// load one wave's B fragments for a K32 unit straight into registers
template<int FN>
__device__ __forceinline__ void loadB(s16x8 (&b)[FN], const char* unit,
                                      int nCols, int bColBase, int kg, int l15) {
#pragma unroll
  for (int fj = 0; fj < FN; ++fj) {
    const int n = bColBase + fj * 16 + l15;
    b[fj] = *reinterpret_cast<const s16x8*>(unit + (kg * nCols + n) * 16);
  }
}

// one K32 step: read A frags from LDS, FM*FN MFMAs with B regs
template<int FM, int FN>
__device__ __forceinline__ void mfma_step(
    const char* lds, int aOff, int aRB, int kByte, int mBase, int l15,
    const s16x8 (&b)[FN], f32x4 (&acc)[FM][FN]) {
  s16x8 a[FM];
#pragma unroll
  for (int fi = 0; fi < FM; ++fi) {
    const int m = mBase + fi * 16 + l15;
    a[fi] = *reinterpret_cast<const s16x8*>(
        lds + aOff + m * aRB + (kByte ^ (((m & 7) << 4) & (aRB - 1))));
  }
#pragma unroll
  for (int fi = 0; fi < FM; ++fi)
#pragma unroll
    for (int fj = 0; fj < FN; ++fj)
      acc[fi][fj] = __builtin_amdgcn_mfma_f32_16x16x32_bf16(a[fi], b[fj], acc[fi][fj], 0, 0, 0);
}

// barrier-free K-loop GEMM: A from LDS, B global->regs (named 2-deep dbuf)
template<int FM, int FN, int KSTEPS>
__device__ __forceinline__ void gemm_reg(
    const char* lds, int aOff, int aRB, int aColBase, int mBase,
    const char* bGlob, int unitStride, int nCols, int bColBase,
    int kg, int l15, f32x4 (&acc)[FM][FN]) {
#pragma unroll
  for (int i = 0; i < FM; ++i)
#pragma unroll
    for (int j = 0; j < FN; ++j) { f32x4 z = {0.f,0.f,0.f,0.f}; acc[i][j] = z; }
  s16x8 bA[FN], bB[FN];
  loadB<FN>(bA, bGlob, nCols, bColBase, kg, l15);
#pragma unroll
  for (int ks = 0; ks < KSTEPS; ks += 2) {
    if (ks + 1 < KSTEPS)
      loadB<FN>(bB, bGlob + (size_t)(ks + 1) * unitStride, nCols, bColBase, kg, l15);
    mfma_step<FM, FN>(lds, aOff, aRB, (aColBase + ks * 32 + kg * 8) * 2,
                      mBase, l15, bA, acc);
    if (ks + 1 < KSTEPS) {
      if (ks + 2 < KSTEPS)
        loadB<FN>(bA, bGlob + (size_t)(ks + 2) * unitStride, nCols, bColBase, kg, l15);
      mfma_step<FM, FN>(lds, aOff, aRB, (aColBase + (ks + 1) * 32 + kg * 8) * 2,
                        mBase, l15, bB, acc);
    }
  }
}

// backbone epilogue, fn=2 chunk: bias (+relu) (+concat relu(xs)) -> outBuf
__device__ __forceinline__ void epi_bb2(char* lds, const f32x4 (&acc)[2][2],
    int outOff, int colBase, const float* bias, int biasLim,
    bool relu, bool concatXS, int lane)
{
  const int l15 = lane & 15, rgrp = lane >> 4;
#pragma unroll
  for (int fj = 0; fj < 2; ++fj) {
    const int gc = colBase + fj * 16 + l15;
    const float bv = (gc < biasLim) ? bias[gc] : 0.f;
#pragma unroll
    for (int fi = 0; fi < 2; ++fi) {
#pragma unroll
      for (int r = 0; r < 4; ++r) {
        const int m = fi * 16 + rgrp * 4 + r;
        float v = acc[fi][fj][r] + bv;
        if (relu) v = fmaxf(v, 0.f);
        u16 hv = f2bf(v);
        if (concatXS && gc >= 482) {
          const int c2 = gc - 482;
          const float xv = bf2f(*reinterpret_cast<const u16*>(
              lds + XS_OFF + m * 128 + ((c2 * 2) ^ ((m & 7) << 4))));
          hv = f2bf(fmaxf(xv, 0.f));
        }
        *reinterpret_cast<u16*>(lds + outOff + m * 1024 + ((gc * 2) ^ ((m & 7) << 4))) = hv;
      }
    }
  }
}

// ---------------- weight prep: fp32 -> bf16 [kg][n][8j] packets ----------------
__global__ __launch_bounds__(256)
void prep_weights(const float* __restrict__ W1, const float* __restrict__ W2,
                  const float* __restrict__ W3, const float* __restrict__ W4,
                  const float* __restrict__ HW1, const float* __restrict__ HW2,
                  const float* __restrict__ HW3, const float* __restrict__ HW4,
                  u16* __restrict__ wp)
{
  for (int idx = blockIdx.x * blockDim.x + threadIdx.x; idx < P_TOT;
       idx += gridDim.x * blockDim.x) {
    float v;
    if (idx < P_L2) {                       // L1: 1 unit [kg4][512n][8], K pad 30->32
      const int e = idx;
      const int kg = e >> 12, n = (e >> 3) & 511, j = e & 7;
      const int k = kg * 8 + j;
      v = (k < 30) ? W1[k * 512 + n] : 0.f;
    } else if (idx < P_L3) {                // L2: 16 units of 16384 elems
      const int e = idx - P_L2;
      const int u = e >> 14, r = e & 16383;
      const int kg = r >> 12, n = (r >> 3) & 511, j = r & 7;
      const int k = u * 32 + kg * 8 + j;
      v = W2[k * 512 + n];
    } else if (idx < P_L4) {                // L3 (cols >= 482 zero)
      const int e = idx - P_L3;
      const int u = e >> 14, r = e & 16383;
      const int kg = r >> 12, n = (r >> 3) & 511, j = r & 7;
      const int k = u * 32 + kg * 8 + j;
      v = (n < 482) ? W3[k * 482 + n] : 0.f;
    } else if (idx < P_H1) {                // L4 packets (unused after fusion; kept)
      const int e = idx - P_L4;
      const int u = e >> 14, r = e & 16383;
      const int kg = r >> 12, n = (r >> 3) & 511, j = r & 7;
      const int k = u * 32 + kg * 8 + j;
      v = W4[k * 512 + n];
    } else if (idx < P_H2) {                // H1: 4 pairs x 16 units [kg4][256n][8]
      const int e = idx - P_H1;
      const int p = e >> 17, r = e & 131071;
      const int u = r >> 13, q = r & 8191;
      const int kg = q >> 11, n = (q >> 3) & 255, j = q & 7;
      const int k = u * 32 + kg * 8 + j;
      const int g = 2 * p + (n >> 7), col = n & 127;
      v = HW1[((size_t)g * 512 + k) * 128 + col];
    } else if (idx < P_H3) {                // H2: 4 pairs x 4 units [kg4][128n][8]
      const int e = idx - P_H2;
      const int p = e >> 14, r = e & 16383;
      const int u = r >> 12, q = r & 4095;
      const int kg = q >> 10, n = (q >> 3) & 127, j = q & 7;
      const int k = u * 32 + kg * 8 + j;
      const int g = 2 * p + (n >> 6), col = n & 63;
      v = HW2[((size_t)g * 128 + k) * 64 + col];
    } else if (idx < P_H4) {                // H3: 4 pairs x 2 units [kg4][64n][8]
      const int e = idx - P_H3;
      const int p = e >> 12, r = e & 4095;
      const int u = r >> 11, q = r & 2047;
      const int kg = q >> 9, n = (q >> 3) & 63, j = q & 7;
      const int k = u * 32 + kg * 8 + j;
      const int g = 2 * p + (n >> 5), col = n & 31;
      v = HW3[((size_t)g * 64 + k) * 32 + col];
    } else {                                // H4: 4 pairs x 1 unit [kg4][32n][8]
      const int e = idx - P_H4;
      const int p = e >> 10, q = e & 1023;
      const int kg = q >> 8, n = (q >> 3) & 31, j = q & 7;
      const int k = kg * 8 + j;
      const int g = 2 * p + (n >> 4), col = n & 15;
      v = HW4[((size_t)g * 32 + k) * 16 + col];
    }
    wp[idx] = f2bf(v);
  }
}

// ---- fused bias: biasF[gc] = Hb1[g][c] + b4 . HW1[g][:,c]  (f32, at wp+P_L4) ----
__global__ __launch_bounds__(256)
void fuse_bias(const float* __restrict__ b4, const float* __restrict__ HW1,
               const float* __restrict__ Hb1, u16* __restrict__ wp)
{
  const int lane = threadIdx.x & 63;
  const int gc = blockIdx.x * 4 + (threadIdx.x >> 6);   // grid 256 -> 1024
  const int g = gc >> 7, c = gc & 127;
  float s = 0.f;
  for (int j = lane; j < 512; j += 64)
    s += b4[j] * HW1[((size_t)g * 512 + j) * 128 + c];
#pragma unroll
  for (int off = 32; off; off >>= 1) s += __shfl_xor(s, off, 64);
  if (lane == 0)
    reinterpret_cast<float*>(wp + P_L4)[gc] = Hb1[g * 128 + c] + s;
}

// ---- fused weight: F = W4 @ HW1 (512 x 1024) -> K32 units at P_F. grid 16. ----
__global__ __launch_bounds__(512, 2)
void fuse_w4h1(const float* __restrict__ W4, u16* __restrict__ wp)
{
  extern __shared__ char lds[];
  const int tid = threadIdx.x;
  const int lane = tid & 63;
  const int l15 = lane & 15, rgrp = lane >> 4, kg = lane >> 4;
  const int wid = __builtin_amdgcn_readfirstlane(tid >> 6);
  const int kb = (blockIdx.x >> 1) * 64;   // rows of F (input dim of W4)
  const int pass = blockIdx.x & 1;
  const char* wpB = reinterpret_cast<const char*>(wp);

  // stage A[r][t] = W4[(kb+r)*512 + t] as bf16, swizzled rows of 1024B
  for (int i = tid; i < 64 * 512; i += 512) {
    const int r = i >> 9, t = i & 511;
    *reinterpret_cast<u16*>(lds + r * 1024 + ((t * 2) ^ ((r & 7) << 4))) =
        f2bf(W4[(size_t)(kb + r) * 512 + t]);
  }
  __syncthreads();

  const int gcW = (pass * 8 + wid) * 64;          // 64-col slab in [0,1024)
  const int p = gcW >> 8, nb = gcW & 255;         // pair + col-in-pair
  f32x4 acc[4][4];
  gemm_reg<4, 4, 16>(lds, 0, 1024, 0, 0,
                     wpB + (size_t)P_H1 * 2 + (size_t)p * 262144, 16384, 256, nb,
                     kg, l15, acc);
#pragma unroll
  for (int fj = 0; fj < 4; ++fj) {
    const int gc = gcW + fj * 16 + l15;
#pragma unroll
    for (int fi = 0; fi < 4; ++fi)
#pragma unroll
      for (int r = 0; r < 4; ++r) {
        const int jin = kb + fi * 16 + rgrp * 4 + r;
        const size_t elem = (size_t)P_F + (size_t)(jin >> 5) * 32768 +
                            (size_t)(((jin >> 3) & 3) * 1024 + gc) * 8 + (jin & 7);
        wp[elem] = f2bf(acc[fi][fj][r]);
      }
  }
}

// ---- fused MLP: TB=32, 68KB LDS -> 2 blocks/CU; fn<=2 chunks, SINGLE-acc L3 ----
// R20 spill root cause: L3 held two acc sets across its chunk gemms (~71 live >
// 64-reg budget at 4 waves/EU). L3 reads buf1, epilogue writes buf0 (disjoint)
// so chunks can run gemm->epi sequentially; ONE barrier after both orders all
// buf1 reads before FH1's y1 writes. Peak live now ~55 everywhere.
__global__ __launch_bounds__(NTHREADS, 4)
__attribute__((amdgpu_waves_per_eu(4, 4)))
void fused_mlp(const float* __restrict__ x, const u16* __restrict__ wp,
               const float* __restrict__ b1, const float* __restrict__ b2,
               const float* __restrict__ b3,
               const float* __restrict__ Hb2, const float* __restrict__ Hb3,
               const float* __restrict__ Hb4,
               const float* __restrict__ hw5, const float* __restrict__ Hb5,
               float* __restrict__ out)
{
  extern __shared__ char lds[];
  const int tid = threadIdx.x;
  const int lane = tid & 63;
  const int l15 = lane & 15;
  const int rgrp = lane >> 4;
  const int kg = lane >> 4;
  const int wid = __builtin_amdgcn_readfirstlane(tid >> 6);  // SGPR: uniform
  const int row0 = blockIdx.x * TB;
  const char* wpB = reinterpret_cast<const char*>(wp);
  const float* biasF = reinterpret_cast<const float*>(wp + P_L4);

  // ---- phase 0: xs = [x, sin x, cos x, 0, 0] bf16, rows 128B swizzled ----
  for (int i = tid; i < TB * 10; i += NTHREADS) {
    const int r = i / 10, c = i % 10;
    const float xv = x[(size_t)(row0 + r) * 10 + c];
    const int sw = (r & 7) << 4;
    char* rowp = lds + XS_OFF + r * 128;
    *reinterpret_cast<u16*>(rowp + ((c * 2) ^ sw)) = f2bf(xv);
    *reinterpret_cast<u16*>(rowp + (((c + 10) * 2) ^ sw)) = f2bf(__sinf(xv));
    *reinterpret_cast<u16*>(rowp + (((c + 20) * 2) ^ sw)) = f2bf(__cosf(xv));
  }
  for (int i = tid; i < TB * 2; i += NTHREADS) {
    const int r = i >> 1, c = 30 + (i & 1);
    *reinterpret_cast<u16*>(lds + XS_OFF + r * 128 + ((c * 2) ^ ((r & 7) << 4))) = 0;
  }
  __syncthreads();

  // ---- L1: xs -> buf0 (two fn=2 chunks, sequential) ----
#pragma unroll
  for (int ch = 0; ch < 2; ++ch) {
    f32x4 acc[2][2];
    gemm_reg<2, 2, 1>(lds, XS_OFF, 128, 0, 0,
                      wpB + (size_t)P_L1 * 2, 8192, 512, wid * 64 + ch * 32, kg, l15, acc);
    epi_bb2(lds, acc, BUF0, wid * 64 + ch * 32, b1, 512, true, false, lane);
  }
  __syncthreads();
  // ---- L2: buf0 -> buf1 ----
#pragma unroll
  for (int ch = 0; ch < 2; ++ch) {
    f32x4 acc[2][2];
    gemm_reg<2, 2, 16>(lds, BUF0, 1024, 0, 0,
                       wpB + (size_t)P_L2 * 2, 32768, 512, wid * 64 + ch * 32, kg, l15, acc);
    epi_bb2(lds, acc, BUF1, wid * 64 + ch * 32, b2, 512, true, false, lane);
  }
  __syncthreads();
  // ---- L3: buf1 -> buf0 (+concat relu(xs)), SINGLE-acc sequential chunks ----
#pragma unroll
  for (int ch = 0; ch < 2; ++ch) {
    f32x4 acc[2][2];
    gemm_reg<2, 2, 16>(lds, BUF1, 1024, 0, 0,
                       wpB + (size_t)P_L3 * 2, 32768, 512, wid * 64 + ch * 32, kg, l15, acc);
    epi_bb2(lds, acc, BUF0, wid * 64 + ch * 32, b3, 482, true, true, lane);
  }
  __syncthreads();   // all buf1 reads done; FH1 may now overwrite y1 region (buf1)

  // ---- heads: FH1 (fused L4+H1, col-split, B read-once) -> wave-private H2..H5 ----
  {
    const int h4 = wid >> 1, chalf = wid & 1;  // FH1 mapping (SGPR)
    const int half = wid & 1;                  // row-half for H2..H5 (16 rows)
    const int mB = half * 16;
    for (int grp = 0; grp < 2; ++grp) {
      if (grp) __syncthreads();      // grp0 slice readers done before overwrite

      // FH1: y1[g1] = relu(L3out @ F + biasF), K=512, fm=2, two fn=2 chunks
      {
        const int g1 = grp * 4 + h4;
        const int y1o = BUF1 + (g1 & 3) * 8192;
#pragma unroll
        for (int ch = 0; ch < 2; ++ch) {
          const int gc0 = g1 * 128 + chalf * 64 + ch * 32;
          f32x4 acc[2][2];
          gemm_reg<2, 2, 16>(lds, BUF0, 1024, 0, 0,
                             wpB + (size_t)P_F * 2, 65536, 1024, gc0, kg, l15, acc);
#pragma unroll
          for (int fj = 0; fj < 2; ++fj) {
            const int chc = chalf * 64 + ch * 32 + fj * 16 + l15;  // col in head
            const float bv = biasF[g1 * 128 + chc];
#pragma unroll
            for (int fi = 0; fi < 2; ++fi)
#pragma unroll
              for (int r = 0; r < 4; ++r) {
                const int m = fi * 16 + rgrp * 4 + r;
                const float v = fmaxf(acc[fi][fj][r] + bv, 0.f);
                *reinterpret_cast<u16*>(lds + y1o + m * 256 + ((chc * 2) ^ ((m & 7) << 4))) = f2bf(v);
              }
          }
        }
      }
      __syncthreads();               // y1 slices complete

      const int g = grp * 4 + (wid >> 1);
      const int pair = g >> 1, side = g & 1;
      const int scrOff = BUF1 + (g & 3) * 8192 + half * 4096;  // own 16 rows
      char* scr = lds + scrOff;

      // H2: y2[16][64] = relu(y1_own_rows @ HW2[g] + Hb2[g]), K=128
      // (both chunk accs computed BEFORE any store: output aliases A cols 0..63;
      //  fm=1 keeps peak live ~51 here)
      {
        f32x4 a2a[1][2], a2b[1][2];
        gemm_reg<1, 2, 4>(lds, scrOff, 256, 0, 0,
                          wpB + (size_t)P_H2 * 2 + (size_t)pair * 32768, 8192, 128,
                          side * 64, kg, l15, a2a);
        gemm_reg<1, 2, 4>(lds, scrOff, 256, 0, 0,
                          wpB + (size_t)P_H2 * 2 + (size_t)pair * 32768, 8192, 128,
                          side * 64 + 32, kg, l15, a2b);
#pragma unroll
        for (int ch = 0; ch < 2; ++ch) {
#pragma unroll
          for (int fj = 0; fj < 2; ++fj) {
            const int c = ch * 32 + fj * 16 + l15;
            const float bv = Hb2[g * 64 + c];
#pragma unroll
            for (int r = 0; r < 4; ++r) {
              const int rl = rgrp * 4 + r;
              const float v = fmaxf((ch ? a2b : a2a)[0][fj][r] + bv, 0.f);
              *reinterpret_cast<u16*>(scr + rl * 256 + ((c * 2) ^ ((rl & 7) << 4))) = f2bf(v);
            }
          }
        }
      }
      // H3: y3[16][32] = relu(y2 @ HW3[g] + Hb3[g]), K=64
      {
        f32x4 a3[1][2];
        gemm_reg<1, 2, 2>(lds, scrOff, 256, 0, 0,
                          wpB + (size_t)P_H3 * 2 + (size_t)pair * 8192, 4096, 64,
                          side * 32, kg, l15, a3);
#pragma unroll
        for (int fj = 0; fj < 2; ++fj) {
          const int c = fj * 16 + l15;
          const float bv = Hb3[g * 32 + c];
#pragma unroll
          for (int r = 0; r < 4; ++r) {
            const int rl = rgrp * 4 + r;
            const float v = fmaxf(a3[0][fj][r] + bv, 0.f);
            *reinterpret_cast<u16*>(scr + rl * 256 + ((c * 2) ^ ((rl & 7) << 4))) = f2bf(v);
          }
        }
      }
      // H4: y4[16][16] = relu(y3 @ HW4[g] + Hb4[g]), K=32
      {
        f32x4 a4[1][1];
        gemm_reg<1, 1, 1>(lds, scrOff, 256, 0, 0,
                          wpB + (size_t)P_H4 * 2 + (size_t)pair * 2048, 2048, 32,
                          side * 16, kg, l15, a4);
        const int c = l15;
        const float bv = Hb4[g * 16 + c];
#pragma unroll
        for (int r = 0; r < 4; ++r) {
          const int rl = rgrp * 4 + r;
          const float v = fmaxf(a4[0][0][r] + bv, 0.f);
          *reinterpret_cast<u16*>(scr + rl * 256 + ((c * 2) ^ ((rl & 7) << 4))) = f2bf(v);
        }
      }
      // H5: out[row][g] = y4 @ HW5[g] + Hb5[g]  (two 8-wide lane partials, 16 rows)
      {
        const int r = lane & 31, kh = lane >> 5;
        float partial = 0.f;
        if (r < 16) {
          const s16x8 y4v = *reinterpret_cast<const s16x8*>(
              scr + r * 256 + ((kh * 16) ^ ((r & 7) << 4)));
#pragma unroll
          for (int j = 0; j < 8; ++j)
            partial += bf2f((u16)y4v[j]) * hw5[g * 16 + kh * 8 + j];
        }
        partial += __shfl_xor(partial, 32, 64);
        if (kh == 0 && r < 16)
          out[(size_t)(row0 + mB + r) * 8 + g] = Hb5[g] + partial;
      }
    }
  }
}

extern "C" void kernel_launch(void* const* d_in, const int* in_sizes, int n_in,
                              void* d_out, int out_size, void* d_ws, size_t ws_size,
                              hipStream_t stream) {
  (void)in_sizes; (void)n_in; (void)out_size; (void)ws_size;
  const float* x   = (const float*)d_in[0];
  const float* W1  = (const float*)d_in[1];
  const float* b1  = (const float*)d_in[2];
  const float* W2  = (const float*)d_in[3];
  const float* b2  = (const float*)d_in[4];
  const float* W3  = (const float*)d_in[5];
  const float* b3  = (const float*)d_in[6];
  const float* W4  = (const float*)d_in[7];
  const float* b4  = (const float*)d_in[8];
  const float* HW1 = (const float*)d_in[9];
  const float* Hb1 = (const float*)d_in[10];
  const float* HW2 = (const float*)d_in[11];
  const float* Hb2 = (const float*)d_in[12];
  const float* HW3 = (const float*)d_in[13];
  const float* Hb3 = (const float*)d_in[14];
  const float* HW4 = (const float*)d_in[15];
  const float* Hb4 = (const float*)d_in[16];
  const float* HW5 = (const float*)d_in[17];
  const float* Hb5 = (const float*)d_in[18];
  float* out = (float*)d_out;
  u16* wp = (u16*)d_ws;

  prep_weights<<<2048, 256, 0, stream>>>(W1, W2, W3, W4, HW1, HW2, HW3, HW4, wp);
  fuse_bias<<<256, 256, 0, stream>>>(b4, HW1, Hb1, wp);
  hipFuncSetAttribute((const void*)fuse_w4h1,
                      hipFuncAttributeMaxDynamicSharedMemorySize, 65536);
  fuse_w4h1<<<16, 512, 65536, stream>>>(W4, wp);

  hipFuncSetAttribute((const void*)fused_mlp,
                      hipFuncAttributeMaxDynamicSharedMemorySize, LDS_BYTES);
  fused_mlp<<<131072 / TB, NTHREADS, LDS_BYTES, stream>>>(
      x, wp, b1, b2, b3, Hb2, Hb3, Hb4, HW5, Hb5, out);
}

// Round 23
// 362.888 us; speedup vs baseline: 1.2707x; 1.2707x over previous
//
#include <hip/hip_runtime.h>
#include <hip/hip_bf16.h>

typedef short s16x8 __attribute__((ext_vector_type(8)));
typedef float f32x4 __attribute__((ext_vector_type(4)));
typedef unsigned short u16;
typedef unsigned int u32;

#define TB 64
#define NTHREADS 512

// prep-buffer element offsets (bf16 elements)
#define P_L1 0
#define P_L2 16384
#define P_L3 278528
#define P_L4 540672      // packets unused after fusion; first 4KB reused for biasF (f32)
#define P_H1 802816
#define P_H2 1327104
#define P_H3 1392640
#define P_H4 1409024
#define P_TOT 1413120
#define P_F  1413120     // fused W4@HW1 packets: 16 units x [kg4][1024n][8j]

// LDS: buf0 [64][1024B] at 0; xs [64][128B] at 64K; buf1 [64][1024B] at 72K.
// chain: xs -(L1)-> buf0 -(L2)-> buf1 -(L3)-> buf0 -(FH1)-> y1 (in buf1)
#define BUF0   0
#define XS_OFF 65536
#define BUF1   73728
#define LDS_BYTES 139264  // 136 KB

__device__ __forceinline__ u16 f2bf(float v) {
  __hip_bfloat16 b = __float2bfloat16(v);
  return __builtin_bit_cast(u16, b);
}
__device__ __forceinline__ float bf2f(u16 u) {
  u32 x = ((u32)u) << 16;
  return __builtin_bit_cast(float, x);
}

// load one wave's B fragments for a K32 unit straight into registers
template<int FN>
__device__ __forceinline__ void loadB(s16x8 (&b)[FN], const char* unit,
                                      int nCols, int bColBase, int kg, int l15) {
#pragma unroll
  for (int fj = 0; fj < FN; ++fj) {
    const int n = bColBase + fj * 16 + l15;
    b[fj] = *reinterpret_cast<const s16x8*>(unit + (kg * nCols + n) * 16);
  }
}

// one K32 step: read A frags from LDS, FM*FN MFMAs with B regs
template<int FM, int FN>
__device__ __forceinline__ void mfma_step(
    const char* lds, int aOff, int aRB, int kByte, int mBase, int l15,
    const s16x8 (&b)[FN], f32x4 (&acc)[FM][FN]) {
  s16x8 a[FM];
#pragma unroll
  for (int fi = 0; fi < FM; ++fi) {
    const int m = mBase + fi * 16 + l15;
    a[fi] = *reinterpret_cast<const s16x8*>(
        lds + aOff + m * aRB + (kByte ^ (((m & 7) << 4) & (aRB - 1))));
  }
#pragma unroll
  for (int fi = 0; fi < FM; ++fi)
#pragma unroll
    for (int fj = 0; fj < FN; ++fj)
      acc[fi][fj] = __builtin_amdgcn_mfma_f32_16x16x32_bf16(a[fi], b[fj], acc[fi][fj], 0, 0, 0);
}

// barrier-free K-loop GEMM: A from LDS, B global->regs (named 2-deep dbuf)
template<int FM, int FN, int KSTEPS>
__device__ __forceinline__ void gemm_reg(
    const char* lds, int aOff, int aRB, int aColBase, int mBase,
    const char* bGlob, int unitStride, int nCols, int bColBase,
    int kg, int l15, f32x4 (&acc)[FM][FN]) {
#pragma unroll
  for (int i = 0; i < FM; ++i)
#pragma unroll
    for (int j = 0; j < FN; ++j) { f32x4 z = {0.f,0.f,0.f,0.f}; acc[i][j] = z; }
  s16x8 bA[FN], bB[FN];
  loadB<FN>(bA, bGlob, nCols, bColBase, kg, l15);
#pragma unroll
  for (int ks = 0; ks < KSTEPS; ks += 2) {
    if (ks + 1 < KSTEPS)
      loadB<FN>(bB, bGlob + (size_t)(ks + 1) * unitStride, nCols, bColBase, kg, l15);
    mfma_step<FM, FN>(lds, aOff, aRB, (aColBase + ks * 32 + kg * 8) * 2,
                      mBase, l15, bA, acc);
    if (ks + 1 < KSTEPS) {
      if (ks + 2 < KSTEPS)
        loadB<FN>(bA, bGlob + (size_t)(ks + 2) * unitStride, nCols, bColBase, kg, l15);
      mfma_step<FM, FN>(lds, aOff, aRB, (aColBase + (ks + 1) * 32 + kg * 8) * 2,
                        mBase, l15, bB, acc);
    }
  }
}

// backbone epilogue: bias (+relu) (+concat relu(xs) cols>=482) -> bf16 -> outBuf
__device__ __forceinline__ void epi_bb(char* lds, const f32x4 (&acc)[4][4],
    int outOff, const float* bias, int biasLim, bool relu, bool concatXS, int tid)
{
  const int lane = tid & 63;
  const int l15 = lane & 15, rgrp = lane >> 4;
  const int wid = __builtin_amdgcn_readfirstlane(tid >> 6);
#pragma unroll
  for (int fj = 0; fj < 4; ++fj) {
    const int gc = wid * 64 + fj * 16 + l15;
    const float bv = (gc < biasLim) ? bias[gc] : 0.f;
#pragma unroll
    for (int fi = 0; fi < 4; ++fi) {
#pragma unroll
      for (int r = 0; r < 4; ++r) {
        const int m = fi * 16 + rgrp * 4 + r;
        float v = acc[fi][fj][r] + bv;
        if (relu) v = fmaxf(v, 0.f);
        u16 hv = f2bf(v);
        if (concatXS && gc >= 482) {
          const int c2 = gc - 482;
          const float xv = bf2f(*reinterpret_cast<const u16*>(
              lds + XS_OFF + m * 128 + ((c2 * 2) ^ ((m & 7) << 4))));
          hv = f2bf(fmaxf(xv, 0.f));
        }
        *reinterpret_cast<u16*>(lds + outOff + m * 1024 + ((gc * 2) ^ ((m & 7) << 4))) = hv;
      }
    }
  }
}

// ---------------- weight prep: fp32 -> bf16 [kg][n][8j] packets ----------------
__global__ __launch_bounds__(256)
void prep_weights(const float* __restrict__ W1, const float* __restrict__ W2,
                  const float* __restrict__ W3, const float* __restrict__ W4,
                  const float* __restrict__ HW1, const float* __restrict__ HW2,
                  const float* __restrict__ HW3, const float* __restrict__ HW4,
                  u16* __restrict__ wp)
{
  for (int idx = blockIdx.x * blockDim.x + threadIdx.x; idx < P_TOT;
       idx += gridDim.x * blockDim.x) {
    float v;
    if (idx < P_L2) {                       // L1: 1 unit [kg4][512n][8], K pad 30->32
      const int e = idx;
      const int kg = e >> 12, n = (e >> 3) & 511, j = e & 7;
      const int k = kg * 8 + j;
      v = (k < 30) ? W1[k * 512 + n] : 0.f;
    } else if (idx < P_L3) {                // L2: 16 units of 16384 elems
      const int e = idx - P_L2;
      const int u = e >> 14, r = e & 16383;
      const int kg = r >> 12, n = (r >> 3) & 511, j = r & 7;
      const int k = u * 32 + kg * 8 + j;
      v = W2[k * 512 + n];
    } else if (idx < P_L4) {                // L3 (cols >= 482 zero)
      const int e = idx - P_L3;
      const int u = e >> 14, r = e & 16383;
      const int kg = r >> 12, n = (r >> 3) & 511, j = r & 7;
      const int k = u * 32 + kg * 8 + j;
      v = (n < 482) ? W3[k * 482 + n] : 0.f;
    } else if (idx < P_H1) {                // L4 packets (unused after fusion; kept)
      const int e = idx - P_L4;
      const int u = e >> 14, r = e & 16383;
      const int kg = r >> 12, n = (r >> 3) & 511, j = r & 7;
      const int k = u * 32 + kg * 8 + j;
      v = W4[k * 512 + n];
    } else if (idx < P_H2) {                // H1: 4 pairs x 16 units [kg4][256n][8]
      const int e = idx - P_H1;
      const int p = e >> 17, r = e & 131071;
      const int u = r >> 13, q = r & 8191;
      const int kg = q >> 11, n = (q >> 3) & 255, j = q & 7;
      const int k = u * 32 + kg * 8 + j;
      const int g = 2 * p + (n >> 7), col = n & 127;
      v = HW1[((size_t)g * 512 + k) * 128 + col];
    } else if (idx < P_H3) {                // H2: 4 pairs x 4 units [kg4][128n][8]
      const int e = idx - P_H2;
      const int p = e >> 14, r = e & 16383;
      const int u = r >> 12, q = r & 4095;
      const int kg = q >> 10, n = (q >> 3) & 127, j = q & 7;
      const int k = u * 32 + kg * 8 + j;
      const int g = 2 * p + (n >> 6), col = n & 63;
      v = HW2[((size_t)g * 128 + k) * 64 + col];
    } else if (idx < P_H4) {                // H3: 4 pairs x 2 units [kg4][64n][8]
      const int e = idx - P_H3;
      const int p = e >> 12, r = e & 4095;
      const int u = r >> 11, q = r & 2047;
      const int kg = q >> 9, n = (q >> 3) & 63, j = q & 7;
      const int k = u * 32 + kg * 8 + j;
      const int g = 2 * p + (n >> 5), col = n & 31;
      v = HW3[((size_t)g * 64 + k) * 32 + col];
    } else {                                // H4: 4 pairs x 1 unit [kg4][32n][8]
      const int e = idx - P_H4;
      const int p = e >> 10, q = e & 1023;
      const int kg = q >> 8, n = (q >> 3) & 31, j = q & 7;
      const int k = kg * 8 + j;
      const int g = 2 * p + (n >> 4), col = n & 15;
      v = HW4[((size_t)g * 32 + k) * 16 + col];
    }
    wp[idx] = f2bf(v);
  }
}

// ---- fused bias: biasF[gc] = Hb1[g][c] + b4 . HW1[g][:,c]  (f32, at wp+P_L4)
//      PARALLEL: one wave per gc. ----
__global__ __launch_bounds__(256)
void fuse_bias(const float* __restrict__ b4, const float* __restrict__ HW1,
               const float* __restrict__ Hb1, u16* __restrict__ wp)
{
  const int lane = threadIdx.x & 63;
  const int gc = blockIdx.x * 4 + (threadIdx.x >> 6);   // grid 256 -> 1024
  const int g = gc >> 7, c = gc & 127;
  float s = 0.f;
  for (int j = lane; j < 512; j += 64)
    s += b4[j] * HW1[((size_t)g * 512 + j) * 128 + c];
#pragma unroll
  for (int off = 32; off; off >>= 1) s += __shfl_xor(s, off, 64);
  if (lane == 0)
    reinterpret_cast<float*>(wp + P_L4)[gc] = Hb1[g * 128 + c] + s;
}

// ---- fused weight: F = W4 @ HW1 (512 x 1024) -> K32 units at P_F. grid 16. ----
__global__ __launch_bounds__(512, 2)
void fuse_w4h1(const float* __restrict__ W4, u16* __restrict__ wp)
{
  extern __shared__ char lds[];
  const int tid = threadIdx.x;
  const int lane = tid & 63;
  const int l15 = lane & 15, rgrp = lane >> 4, kg = lane >> 4;
  const int wid = __builtin_amdgcn_readfirstlane(tid >> 6);
  const int kb = (blockIdx.x >> 1) * 64;   // rows of F (input dim of W4)
  const int pass = blockIdx.x & 1;
  const char* wpB = reinterpret_cast<const char*>(wp);

  // stage A[r][t] = W4[(kb+r)*512 + t] as bf16, swizzled rows of 1024B
  for (int i = tid; i < 64 * 512; i += 512) {
    const int r = i >> 9, t = i & 511;
    *reinterpret_cast<u16*>(lds + r * 1024 + ((t * 2) ^ ((r & 7) << 4))) =
        f2bf(W4[(size_t)(kb + r) * 512 + t]);
  }
  __syncthreads();

  const int gcW = (pass * 8 + wid) * 64;          // 64-col slab in [0,1024)
  const int p = gcW >> 8, nb = gcW & 255;         // pair + col-in-pair
  f32x4 acc[4][4];
  gemm_reg<4, 4, 16>(lds, 0, 1024, 0, 0,
                     wpB + (size_t)P_H1 * 2 + (size_t)p * 262144, 16384, 256, nb,
                     kg, l15, acc);
#pragma unroll
  for (int fj = 0; fj < 4; ++fj) {
    const int gc = gcW + fj * 16 + l15;
#pragma unroll
    for (int fi = 0; fi < 4; ++fi)
#pragma unroll
      for (int r = 0; r < 4; ++r) {
        const int jin = kb + fi * 16 + rgrp * 4 + r;
        const size_t elem = (size_t)P_F + (size_t)(jin >> 5) * 32768 +
                            (size_t)(((jin >> 3) & 3) * 1024 + gc) * 8 + (jin & 7);
        wp[elem] = f2bf(acc[fi][fj][r]);
      }
  }
}

// ---- fused MLP: 8 waves, L4 fused into H1 (FH1), wave-private H2+ ----
__global__ __launch_bounds__(NTHREADS, 2)
void fused_mlp(const float* __restrict__ x, const u16* __restrict__ wp,
               const float* __restrict__ b1, const float* __restrict__ b2,
               const float* __restrict__ b3,
               const float* __restrict__ Hb2, const float* __restrict__ Hb3,
               const float* __restrict__ Hb4,
               const float* __restrict__ hw5, const float* __restrict__ Hb5,
               float* __restrict__ out)
{
  extern __shared__ char lds[];
  const int tid = threadIdx.x;
  const int lane = tid & 63;
  const int l15 = lane & 15;
  const int rgrp = lane >> 4;
  const int kg = lane >> 4;
  const int wid = __builtin_amdgcn_readfirstlane(tid >> 6);  // SGPR: uniform
  const int row0 = blockIdx.x * TB;
  const char* wpB = reinterpret_cast<const char*>(wp);
  const float* biasF = reinterpret_cast<const float*>(wp + P_L4);

  // ---- phase 0: xs = [x, sin x, cos x, 0, 0] bf16, rows 128B swizzled ----
  for (int i = tid; i < TB * 10; i += NTHREADS) {
    const int r = i / 10, c = i % 10;
    const float xv = x[(size_t)(row0 + r) * 10 + c];
    const int sw = (r & 7) << 4;
    char* rowp = lds + XS_OFF + r * 128;
    *reinterpret_cast<u16*>(rowp + ((c * 2) ^ sw)) = f2bf(xv);
    *reinterpret_cast<u16*>(rowp + (((c + 10) * 2) ^ sw)) = f2bf(__sinf(xv));
    *reinterpret_cast<u16*>(rowp + (((c + 20) * 2) ^ sw)) = f2bf(__cosf(xv));
  }
  for (int i = tid; i < TB * 2; i += NTHREADS) {
    const int r = i >> 1, c = 30 + (i & 1);
    *reinterpret_cast<u16*>(lds + XS_OFF + r * 128 + ((c * 2) ^ ((r & 7) << 4))) = 0;
  }
  __syncthreads();

  // ---- L1: xs -> buf0 ----
  {
    f32x4 acc[4][4];
    gemm_reg<4, 4, 1>(lds, XS_OFF, 128, 0, 0,
                      wpB + (size_t)P_L1 * 2, 8192, 512, wid * 64, kg, l15, acc);
    epi_bb(lds, acc, BUF0, b1, 512, true, false, tid);
    __syncthreads();
  }
  // ---- L2: buf0 -> buf1 ----
  {
    f32x4 acc[4][4];
    gemm_reg<4, 4, 16>(lds, BUF0, 1024, 0, 0,
                       wpB + (size_t)P_L2 * 2, 32768, 512, wid * 64, kg, l15, acc);
    epi_bb(lds, acc, BUF1, b2, 512, true, false, tid);
    __syncthreads();
  }
  // ---- L3: buf1 -> buf0 (+concat relu(xs)) ----
  {
    f32x4 acc[4][4];
    gemm_reg<4, 4, 16>(lds, BUF1, 1024, 0, 0,
                       wpB + (size_t)P_L3 * 2, 32768, 512, wid * 64, kg, l15, acc);
    __syncthreads();                 // buf1 reads done before y1 slices overwrite it
    epi_bb(lds, acc, BUF0, b3, 482, true, true, tid);
    __syncthreads();
  }

  // ---- heads: FH1 (fused L4+H1, col-split, B read-once) -> wave-private H2..H5 ----
  {
    const int h4 = wid >> 1, chalf = wid & 1;  // FH1 mapping (SGPR)
    const int half = wid & 1;                  // row-half for H2..H5
    const int mB = half * 32;
    for (int grp = 0; grp < 2; ++grp) {
      if (grp) __syncthreads();      // grp0 slice readers done before overwrite

      // FH1: y1[g1] = relu(L3out @ F[:,g1 cols] + biasF), K=512, fm=4 all rows
      {
        const int g1 = grp * 4 + h4;
        const int gc0 = g1 * 128 + chalf * 64;
        f32x4 acc[4][4];
        gemm_reg<4, 4, 16>(lds, BUF0, 1024, 0, 0,
                           wpB + (size_t)P_F * 2, 65536, 1024, gc0, kg, l15, acc);
        const int y1o = BUF1 + (g1 & 3) * 16384;
#pragma unroll
        for (int fj = 0; fj < 4; ++fj) {
          const int ch = chalf * 64 + fj * 16 + l15;        // col in head 0..127
          const float bv = biasF[g1 * 128 + ch];
#pragma unroll
          for (int fi = 0; fi < 4; ++fi)
#pragma unroll
            for (int r = 0; r < 4; ++r) {
              const int m = fi * 16 + rgrp * 4 + r;
              const float v = fmaxf(acc[fi][fj][r] + bv, 0.f);
              *reinterpret_cast<u16*>(lds + y1o + m * 256 + ((ch * 2) ^ ((m & 7) << 4))) = f2bf(v);
            }
        }
      }
      __syncthreads();               // y1 slices complete

      const int g = grp * 4 + (wid >> 1);
      const int pair = g >> 1, side = g & 1;
      const int scrOff = BUF1 + (g & 3) * 16384 + half * 8192;  // own 32 rows
      char* scr = lds + scrOff;

      // H2: y2[32][64] = relu(y1_own_rows @ HW2[g] + Hb2[g]), K=128
      {
        f32x4 a2[2][4];
        gemm_reg<2, 4, 4>(lds, scrOff, 256, 0, 0,
                          wpB + (size_t)P_H2 * 2 + (size_t)pair * 32768, 8192, 128,
                          side * 64, kg, l15, a2);
#pragma unroll
        for (int fj = 0; fj < 4; ++fj) {
          const int c = fj * 16 + l15;
          const float bv = Hb2[g * 64 + c];
#pragma unroll
          for (int fi = 0; fi < 2; ++fi)
#pragma unroll
            for (int r = 0; r < 4; ++r) {
              const int rl = fi * 16 + rgrp * 4 + r;
              const float v = fmaxf(a2[fi][fj][r] + bv, 0.f);
              *reinterpret_cast<u16*>(scr + rl * 256 + ((c * 2) ^ ((rl & 7) << 4))) = f2bf(v);
            }
        }
      }
      // H3: y3[32][32] = relu(y2 @ HW3[g] + Hb3[g]), K=64
      {
        f32x4 a3[2][2];
        gemm_reg<2, 2, 2>(lds, scrOff, 256, 0, 0,
                          wpB + (size_t)P_H3 * 2 + (size_t)pair * 8192, 4096, 64,
                          side * 32, kg, l15, a3);
#pragma unroll
        for (int fj = 0; fj < 2; ++fj) {
          const int c = fj * 16 + l15;
          const float bv = Hb3[g * 32 + c];
#pragma unroll
          for (int fi = 0; fi < 2; ++fi)
#pragma unroll
            for (int r = 0; r < 4; ++r) {
              const int rl = fi * 16 + rgrp * 4 + r;
              const float v = fmaxf(a3[fi][fj][r] + bv, 0.f);
              *reinterpret_cast<u16*>(scr + rl * 256 + ((c * 2) ^ ((rl & 7) << 4))) = f2bf(v);
            }
        }
      }
      // H4: y4[32][16] = relu(y3 @ HW4[g] + Hb4[g]), K=32
      {
        f32x4 a4[2][1];
        gemm_reg<2, 1, 1>(lds, scrOff, 256, 0, 0,
                          wpB + (size_t)P_H4 * 2 + (size_t)pair * 2048, 2048, 32,
                          side * 16, kg, l15, a4);
        const int c = l15;
        const float bv = Hb4[g * 16 + c];
#pragma unroll
        for (int fi = 0; fi < 2; ++fi)
#pragma unroll
          for (int r = 0; r < 4; ++r) {
            const int rl = fi * 16 + rgrp * 4 + r;
            const float v = fmaxf(a4[fi][0][r] + bv, 0.f);
            *reinterpret_cast<u16*>(scr + rl * 256 + ((c * 2) ^ ((rl & 7) << 4))) = f2bf(v);
          }
      }
      // H5: out[row][g] = y4 @ HW5[g] + Hb5[g]  (two 8-wide lane partials)
      {
        const int r = lane & 31, kh = lane >> 5;
        const s16x8 y4v = *reinterpret_cast<const s16x8*>(
            scr + r * 256 + ((kh * 16) ^ ((r & 7) << 4)));
        float partial = 0.f;
#pragma unroll
        for (int j = 0; j < 8; ++j)
          partial += bf2f((u16)y4v[j]) * hw5[g * 16 + kh * 8 + j];
        partial += __shfl_xor(partial, 32, 64);
        if (kh == 0)
          out[(size_t)(row0 + mB + r) * 8 + g] = Hb5[g] + partial;
      }
    }
  }
}

extern "C" void kernel_launch(void* const* d_in, const int* in_sizes, int n_in,
                              void* d_out, int out_size, void* d_ws, size_t ws_size,
                              hipStream_t stream) {
  (void)in_sizes; (void)n_in; (void)out_size; (void)ws_size;
  const float* x   = (const float*)d_in[0];
  const float* W1  = (const float*)d_in[1];
  const float* b1  = (const float*)d_in[2];
  const float* W2  = (const float*)d_in[3];
  const float* b2  = (const float*)d_in[4];
  const float* W3  = (const float*)d_in[5];
  const float* b3  = (const float*)d_in[6];
  const float* W4  = (const float*)d_in[7];
  const float* b4  = (const float*)d_in[8];
  const float* HW1 = (const float*)d_in[9];
  const float* Hb1 = (const float*)d_in[10];
  const float* HW2 = (const float*)d_in[11];
  const float* Hb2 = (const float*)d_in[12];
  const float* HW3 = (const float*)d_in[13];
  const float* Hb3 = (const float*)d_in[14];
  const float* HW4 = (const float*)d_in[15];
  const float* Hb4 = (const float*)d_in[16];
  const float* HW5 = (const float*)d_in[17];
  const float* Hb5 = (const float*)d_in[18];
  float* out = (float*)d_out;
  u16* wp = (u16*)d_ws;

  prep_weights<<<2048, 256, 0, stream>>>(W1, W2, W3, W4, HW1, HW2, HW3, HW4, wp);
  fuse_bias<<<256, 256, 0, stream>>>(b4, HW1, Hb1, wp);
  hipFuncSetAttribute((const void*)fuse_w4h1,
                      hipFuncAttributeMaxDynamicSharedMemorySize, 65536);
  fuse_w4h1<<<16, 512, 65536, stream>>>(W4, wp);

  hipFuncSetAttribute((const void*)fused_mlp,
                      hipFuncAttributeMaxDynamicSharedMemorySize, LDS_BYTES);
  fused_mlp<<<131072 / TB, NTHREADS, LDS_BYTES, stream>>>(
      x, wp, b1, b2, b3, Hb2, Hb3, Hb4, HW5, Hb5, out);
}